// Round 3
// baseline (1035.060 us; speedup 1.0000x reference)
//
#include <hip/hip_runtime.h>

// GraphSAGE (pool aggregator), 2 layers + linear head.
// N=100000, E=1600000, IN=128, H=64, C=2.
// Edge aggregation: 128-node dst bins built per call (packed (src<<7)|local),
// then per-bin LDS-tile max with ds atomics. pooled1 kept as packed bf16 to
// halve the dominant random-gather traffic. All maxes order-invariant ->
// deterministic output despite atomicAdd ordering in the bin build.

#define BIN_CAP 3072  // >> Poisson(2046) tail; P(overflow) ~ e^-221

__device__ __forceinline__ unsigned bf16rne(float f) {
  const unsigned u = __float_as_uint(f);
  return (u + 0x7FFFu + ((u >> 16) & 1u)) >> 16;
}

// ---------------- GEMM: pooled1 = relu(x @ W[128x128] + b), bf16-packed out ----
__global__ __launch_bounds__(256) void gemm_pool1(
    const float* __restrict__ A, const float* __restrict__ W,
    const float* __restrict__ b, unsigned* __restrict__ out, int n) {
  __shared__ float As[128][36];
  const int t = threadIdx.x;
  const int row0 = blockIdx.x * 32;
  const int tr = t & 31;
  const int tk = t >> 5;
  int gr = row0 + tr; if (gr >= n) gr = n - 1;
#pragma unroll
  for (int i = 0; i < 4; ++i) {
    const int k4 = tk * 16 + i * 4;
    const float4 v = *(const float4*)(A + (size_t)gr * 128 + k4);
    As[k4 + 0][tr] = v.x; As[k4 + 1][tr] = v.y;
    As[k4 + 2][tr] = v.z; As[k4 + 3][tr] = v.w;
  }
  __syncthreads();
  const int cg = t & 31, rg = t >> 5;
  const int c0 = cg * 4;
  float acc[4][4] = {};
#pragma unroll 4
  for (int k = 0; k < 128; ++k) {
    const float4 w = *(const float4*)(W + k * 128 + c0);
    const float4 a = *(const float4*)(&As[k][rg * 4]);
    acc[0][0] = fmaf(a.x, w.x, acc[0][0]);
    acc[0][1] = fmaf(a.x, w.y, acc[0][1]);
    acc[0][2] = fmaf(a.x, w.z, acc[0][2]);
    acc[0][3] = fmaf(a.x, w.w, acc[0][3]);
    acc[1][0] = fmaf(a.y, w.x, acc[1][0]);
    acc[1][1] = fmaf(a.y, w.y, acc[1][1]);
    acc[1][2] = fmaf(a.y, w.z, acc[1][2]);
    acc[1][3] = fmaf(a.y, w.w, acc[1][3]);
    acc[2][0] = fmaf(a.z, w.x, acc[2][0]);
    acc[2][1] = fmaf(a.z, w.y, acc[2][1]);
    acc[2][2] = fmaf(a.z, w.z, acc[2][2]);
    acc[2][3] = fmaf(a.z, w.w, acc[2][3]);
    acc[3][0] = fmaf(a.w, w.x, acc[3][0]);
    acc[3][1] = fmaf(a.w, w.y, acc[3][1]);
    acc[3][2] = fmaf(a.w, w.z, acc[3][2]);
    acc[3][3] = fmaf(a.w, w.w, acc[3][3]);
  }
  const float4 bb = *(const float4*)(b + c0);
#pragma unroll
  for (int r = 0; r < 4; ++r) {
    const int orow = row0 + rg * 4 + r;
    if (orow < n) {
      const float v0 = fmaxf(acc[r][0] + bb.x, 0.f);
      const float v1 = fmaxf(acc[r][1] + bb.y, 0.f);
      const float v2 = fmaxf(acc[r][2] + bb.z, 0.f);
      const float v3 = fmaxf(acc[r][3] + bb.w, 0.f);
      uint2 o;
      o.x = bf16rne(v0) | (bf16rne(v1) << 16);
      o.y = bf16rne(v2) | (bf16rne(v3) << 16);
      *(uint2*)(out + (size_t)orow * 64 + (c0 >> 1)) = o;
    }
  }
}

// ---------------- bin build: edges -> 128-node dst bins ----------------
__global__ __launch_bounds__(256) void bin_scatter(
    const int* __restrict__ src, const int* __restrict__ dst,
    unsigned* __restrict__ binCursor, unsigned* __restrict__ ebuf, int nE) {
  const int e = blockIdx.x * 256 + threadIdx.x;
  if (e >= nE) return;
  const int d = dst[e];
  const int bin = d >> 7;
  const unsigned word = ((unsigned)src[e] << 7) | (unsigned)(d & 127);
  const unsigned pos = atomicAdd(&binCursor[bin], 1u);
  if (pos < BIN_CAP) ebuf[(size_t)bin * BIN_CAP + pos] = word;
}

// ---------------- per-bin max, D=128, bf16-packed pooled ----------------
// LDS tile: permuted feature layout: feat f -> word ((f&1)<<6)|(f>>1)
// so the two ds_max per edge are each bank-conflict-free.
__global__ __launch_bounds__(512) void agg_bin128(
    const unsigned* __restrict__ ebuf, const unsigned* __restrict__ binCnt,
    const unsigned* __restrict__ pooled, float* __restrict__ agg, int n) {
  __shared__ unsigned tile[128 * 128];
  const int b = blockIdx.x;
  const int t = threadIdx.x;
  for (int i = t * 4; i < 16384; i += 2048)
    *(uint4*)&tile[i] = uint4{0u, 0u, 0u, 0u};
  __syncthreads();
  unsigned cnt = binCnt[b]; if (cnt > BIN_CAP) cnt = BIN_CAP;
  const int w = t >> 6, lane = t & 63;
  const unsigned* eb = ebuf + (size_t)b * BIN_CAP;
  for (unsigned e = (unsigned)w; e < cnt; e += 8) {
    const unsigned word = eb[e];
    const unsigned s = word >> 7;
    const int local = (int)(word & 127u);
    const unsigned v = pooled[(size_t)s * 64 + lane];  // feats 2*lane | 2*lane+1
    unsigned* row = &tile[local << 7];
    atomicMax(&row[lane], v << 16);              // even feat (bf16 -> f32 bits)
    atomicMax(&row[64 + lane], v & 0xFFFF0000u); // odd feat
  }
  __syncthreads();
  const int base = b << 7;
  for (int i = t * 4; i < 16384; i += 2048) {
    const int r = i >> 7, c = i & 127;  // c % 4 == 0
    if (base + r < n) {
      const unsigned* row = &tile[r << 7];
      uint4 o;
      o.x = row[(c >> 1) + 0];        // feat c   (even)
      o.y = row[64 + (c >> 1) + 0];   // feat c+1 (odd)
      o.z = row[(c >> 1) + 1];        // feat c+2
      o.w = row[64 + (c >> 1) + 1];   // feat c+3
      *(uint4*)((unsigned*)agg + (size_t)(base + r) * 128 + c) = o;
    }
  }
}

// ---------------- per-bin max, D=64, fp32 pooled ----------------
__global__ __launch_bounds__(512) void agg_bin64(
    const unsigned* __restrict__ ebuf, const unsigned* __restrict__ binCnt,
    const float* __restrict__ pooled, float* __restrict__ agg, int n) {
  __shared__ unsigned tile[128 * 64];
  const int b = blockIdx.x;
  const int t = threadIdx.x;
  for (int i = t * 4; i < 8192; i += 2048)
    *(uint4*)&tile[i] = uint4{0u, 0u, 0u, 0u};
  __syncthreads();
  unsigned cnt = binCnt[b]; if (cnt > BIN_CAP) cnt = BIN_CAP;
  const int w = t >> 6, lane = t & 63;
  const unsigned* eb = ebuf + (size_t)b * BIN_CAP;
  for (unsigned e = (unsigned)w; e < cnt; e += 8) {
    const unsigned word = eb[e];
    const unsigned s = word >> 7;
    const int local = (int)(word & 127u);
    const unsigned v = __float_as_uint(pooled[(size_t)s * 64 + lane]);
    atomicMax(&tile[(local << 6) + lane], v);
  }
  __syncthreads();
  const int base = b << 7;
  for (int i = t * 4; i < 8192; i += 2048) {
    const int r = i >> 6;
    if (base + r < n)
      *(uint4*)((unsigned*)agg + (size_t)(base + r) * 64 + (i & 63)) =
          *(const uint4*)&tile[i];
  }
}

// ---------------- h = relu?(A @ Wa [+ G @ Wg] + bias), DOUT=64 ----------------
template <int DIN, bool DUAL, bool RELU>
__global__ __launch_bounds__(256) void gemm_h(
    const float* __restrict__ A, const float* __restrict__ Wa,
    const float* __restrict__ G, const float* __restrict__ Wg,
    const float* __restrict__ bias, float* __restrict__ out, int n) {
  __shared__ float S[DIN][68];
  const int t = threadIdx.x;
  const int row0 = blockIdx.x * 64;
  const int tr = t & 63;
  const int tk = t >> 6;
  const int cg = t & 15, rg = t >> 4;
  const int c0 = cg * 4;
  float acc[4][4] = {};
  int gr = row0 + tr; if (gr >= n) gr = n - 1;
  const int NPASS = DUAL ? 2 : 1;
  for (int pass = 0; pass < NPASS; ++pass) {
    const float* __restrict__ P = pass ? G : A;
    const float* __restrict__ W = pass ? Wg : Wa;
    constexpr int PER_T = DIN / 16;
#pragma unroll
    for (int i = 0; i < PER_T; ++i) {
      const int k4 = (tk * PER_T + i) * 4;
      const float4 v = *(const float4*)(P + (size_t)gr * DIN + k4);
      S[k4 + 0][tr] = v.x; S[k4 + 1][tr] = v.y;
      S[k4 + 2][tr] = v.z; S[k4 + 3][tr] = v.w;
    }
    __syncthreads();
#pragma unroll 4
    for (int k = 0; k < DIN; ++k) {
      const float4 w = *(const float4*)(W + k * 64 + c0);
      const float4 a = *(const float4*)(&S[k][rg * 4]);
      acc[0][0] = fmaf(a.x, w.x, acc[0][0]);
      acc[0][1] = fmaf(a.x, w.y, acc[0][1]);
      acc[0][2] = fmaf(a.x, w.z, acc[0][2]);
      acc[0][3] = fmaf(a.x, w.w, acc[0][3]);
      acc[1][0] = fmaf(a.y, w.x, acc[1][0]);
      acc[1][1] = fmaf(a.y, w.y, acc[1][1]);
      acc[1][2] = fmaf(a.y, w.z, acc[1][2]);
      acc[1][3] = fmaf(a.y, w.w, acc[1][3]);
      acc[2][0] = fmaf(a.z, w.x, acc[2][0]);
      acc[2][1] = fmaf(a.z, w.y, acc[2][1]);
      acc[2][2] = fmaf(a.z, w.z, acc[2][2]);
      acc[2][3] = fmaf(a.z, w.w, acc[2][3]);
      acc[3][0] = fmaf(a.w, w.x, acc[3][0]);
      acc[3][1] = fmaf(a.w, w.y, acc[3][1]);
      acc[3][2] = fmaf(a.w, w.z, acc[3][2]);
      acc[3][3] = fmaf(a.w, w.w, acc[3][3]);
    }
    if (pass + 1 < NPASS) __syncthreads();
  }
  const float4 bb = *(const float4*)(bias + c0);
#pragma unroll
  for (int r = 0; r < 4; ++r) {
    const int orow = row0 + rg * 4 + r;
    if (orow < n) {
      float4 o;
      o.x = acc[r][0] + bb.x;
      o.y = acc[r][1] + bb.y;
      o.z = acc[r][2] + bb.z;
      o.w = acc[r][3] + bb.w;
      if (RELU) {
        o.x = fmaxf(o.x, 0.f); o.y = fmaxf(o.y, 0.f);
        o.z = fmaxf(o.z, 0.f); o.w = fmaxf(o.w, 0.f);
      }
      *(float4*)(out + (size_t)orow * 64 + c0) = o;
    }
  }
}

// ---------------- out[N x 2] = h2 @ W_out + b_out ----------------
__global__ __launch_bounds__(256) void out_linear(
    const float* __restrict__ h, const float* __restrict__ W,
    const float* __restrict__ b, float* __restrict__ out, int n) {
  const int node = blockIdx.x * 256 + threadIdx.x;
  if (node >= n) return;
  float a0 = b[0], a1 = b[1];
#pragma unroll
  for (int k = 0; k < 64; k += 4) {
    const float4 hv = *(const float4*)(h + (size_t)node * 64 + k);
    a0 = fmaf(hv.x, W[(k + 0) * 2 + 0], a0);
    a1 = fmaf(hv.x, W[(k + 0) * 2 + 1], a1);
    a0 = fmaf(hv.y, W[(k + 1) * 2 + 0], a0);
    a1 = fmaf(hv.y, W[(k + 1) * 2 + 1], a1);
    a0 = fmaf(hv.z, W[(k + 2) * 2 + 0], a0);
    a1 = fmaf(hv.z, W[(k + 2) * 2 + 1], a1);
    a0 = fmaf(hv.w, W[(k + 3) * 2 + 0], a0);
    a1 = fmaf(hv.w, W[(k + 3) * 2 + 1], a1);
  }
  float2 o; o.x = a0; o.y = a1;
  *(float2*)(out + (size_t)node * 2) = o;
}

extern "C" void kernel_launch(void* const* d_in, const int* in_sizes, int n_in,
                              void* d_out, int out_size, void* d_ws, size_t ws_size,
                              hipStream_t stream) {
  const float* x       = (const float*)d_in[0];
  const int*   src     = (const int*)d_in[1];
  const int*   dst     = (const int*)d_in[2];
  const float* W_pool1 = (const float*)d_in[3];
  const float* b_pool1 = (const float*)d_in[4];
  const float* W_self1 = (const float*)d_in[5];
  const float* W_neigh1= (const float*)d_in[6];
  const float* b1      = (const float*)d_in[7];
  const float* W_pool2 = (const float*)d_in[8];
  const float* b_pool2 = (const float*)d_in[9];
  const float* W_self2 = (const float*)d_in[10];
  const float* W_neigh2= (const float*)d_in[11];
  const float* b2      = (const float*)d_in[12];
  const float* W_out   = (const float*)d_in[13];
  const float* b_out   = (const float*)d_in[14];

  const int n  = in_sizes[0] / 128;
  const int nE = in_sizes[1];
  const int NB = (n + 127) >> 7;

  // workspace layout:
  float* A = (float*)d_ws;                 // n*128 floats
  float* B = A + (size_t)n * 128;          // n*128 floats
  unsigned* ebuf = (unsigned*)(B + (size_t)n * 128);  // NB*BIN_CAP
  unsigned* binCursor = ebuf + (size_t)NB * BIN_CAP;  // NB

  unsigned* pooled1 = (unsigned*)A;        // n*64 words (bf16x2), dead after agg1
  float* h1      = A;                      // n*64 f (overwrites pooled1)
  float* pooled2 = A + (size_t)n * 64;     // n*64 f
  float* agg1    = B;                      // n*128 f, dead after gemm_h layer1
  float* agg2    = B;                      // n*64 f
  float* h2      = B + (size_t)n * 64;     // n*64 f
  float* outp    = (float*)d_out;

  // ---- bin build ----
  hipMemsetAsync(binCursor, 0, (size_t)NB * sizeof(unsigned), stream);
  bin_scatter<<<(nE + 255) / 256, 256, 0, stream>>>(src, dst, binCursor, ebuf, nE);

  // ---- layer 1 ----
  gemm_pool1<<<(n + 31) / 32, 256, 0, stream>>>(x, W_pool1, b_pool1, pooled1, n);
  agg_bin128<<<NB, 512, 0, stream>>>(ebuf, binCursor, pooled1, agg1, n);
  gemm_h<128, true, true><<<(n + 63) / 64, 256, 0, stream>>>(
      x, W_self1, agg1, W_neigh1, b1, h1, n);

  // ---- layer 2 ----
  gemm_h<64, false, true><<<(n + 63) / 64, 256, 0, stream>>>(
      h1, W_pool2, nullptr, nullptr, b_pool2, pooled2, n);
  agg_bin64<<<NB, 512, 0, stream>>>(ebuf, binCursor, pooled2, agg2, n);
  gemm_h<64, true, true><<<(n + 63) / 64, 256, 0, stream>>>(
      h1, W_self2, agg2, W_neigh2, b2, h2, n);

  // ---- head ----
  out_linear<<<(n + 255) / 256, 256, 0, stream>>>(h2, W_out, b_out, outp, n);
}

// Round 4
// 368.677 us; speedup vs baseline: 2.8075x; 2.8075x over previous
//
#include <hip/hip_runtime.h>

// GraphSAGE (pool aggregator), 2 layers + linear head.
// N=100000, E=1600000, IN=128, H=64, C=2.
// Edge aggregation: two-level 128-node dst binning (LDS histogram + one
// global atomicAdd per block*bin), then per-bin LDS-tile max with ds atomics,
// ILP-8 edge processing. pooled1 packed bf16 to halve gather traffic.
// All maxes order-invariant -> deterministic output.

#define BIN_CAP 3072   // mean bin load 2048, sd ~45; 3072 is ~22 sigma
#define MAX_BINS 1024
#define SCHUNK 8192    // edges per scatter block

__device__ __forceinline__ unsigned bf16rne(float f) {
  const unsigned u = __float_as_uint(f);
  return (u + 0x7FFFu + ((u >> 16) & 1u)) >> 16;
}

// ---------------- GEMM: pooled1 = relu(x @ W[128x128] + b), bf16-packed out ----
__global__ __launch_bounds__(256) void gemm_pool1(
    const float* __restrict__ A, const float* __restrict__ W,
    const float* __restrict__ b, unsigned* __restrict__ out, int n) {
  __shared__ float As[128][36];
  const int t = threadIdx.x;
  const int row0 = blockIdx.x * 32;
  const int tr = t & 31;
  const int tk = t >> 5;
  int gr = row0 + tr; if (gr >= n) gr = n - 1;
#pragma unroll
  for (int i = 0; i < 4; ++i) {
    const int k4 = tk * 16 + i * 4;
    const float4 v = *(const float4*)(A + (size_t)gr * 128 + k4);
    As[k4 + 0][tr] = v.x; As[k4 + 1][tr] = v.y;
    As[k4 + 2][tr] = v.z; As[k4 + 3][tr] = v.w;
  }
  __syncthreads();
  const int cg = t & 31, rg = t >> 5;
  const int c0 = cg * 4;
  float acc[4][4] = {};
#pragma unroll 4
  for (int k = 0; k < 128; ++k) {
    const float4 w = *(const float4*)(W + k * 128 + c0);
    const float4 a = *(const float4*)(&As[k][rg * 4]);
    acc[0][0] = fmaf(a.x, w.x, acc[0][0]);
    acc[0][1] = fmaf(a.x, w.y, acc[0][1]);
    acc[0][2] = fmaf(a.x, w.z, acc[0][2]);
    acc[0][3] = fmaf(a.x, w.w, acc[0][3]);
    acc[1][0] = fmaf(a.y, w.x, acc[1][0]);
    acc[1][1] = fmaf(a.y, w.y, acc[1][1]);
    acc[1][2] = fmaf(a.y, w.z, acc[1][2]);
    acc[1][3] = fmaf(a.y, w.w, acc[1][3]);
    acc[2][0] = fmaf(a.z, w.x, acc[2][0]);
    acc[2][1] = fmaf(a.z, w.y, acc[2][1]);
    acc[2][2] = fmaf(a.z, w.z, acc[2][2]);
    acc[2][3] = fmaf(a.z, w.w, acc[2][3]);
    acc[3][0] = fmaf(a.w, w.x, acc[3][0]);
    acc[3][1] = fmaf(a.w, w.y, acc[3][1]);
    acc[3][2] = fmaf(a.w, w.z, acc[3][2]);
    acc[3][3] = fmaf(a.w, w.w, acc[3][3]);
  }
  const float4 bb = *(const float4*)(b + c0);
#pragma unroll
  for (int r = 0; r < 4; ++r) {
    const int orow = row0 + rg * 4 + r;
    if (orow < n) {
      const float v0 = fmaxf(acc[r][0] + bb.x, 0.f);
      const float v1 = fmaxf(acc[r][1] + bb.y, 0.f);
      const float v2 = fmaxf(acc[r][2] + bb.z, 0.f);
      const float v3 = fmaxf(acc[r][3] + bb.w, 0.f);
      uint2 o;
      o.x = bf16rne(v0) | (bf16rne(v1) << 16);
      o.y = bf16rne(v2) | (bf16rne(v3) << 16);
      *(uint2*)(out + (size_t)orow * 64 + (c0 >> 1)) = o;
    }
  }
}

// ---------------- two-level bin scatter ----------------
// Per block: LDS histogram over bins -> one global atomicAdd per touched bin
// to reserve a contiguous range -> scatter via LDS cursors.
__global__ __launch_bounds__(256) void bin_scatter2(
    const int* __restrict__ src, const int* __restrict__ dst,
    unsigned* __restrict__ binCursor, unsigned* __restrict__ ebuf,
    int nE, int nb) {
  __shared__ int hist[MAX_BINS];
  __shared__ int base[MAX_BINS];
  const int t = threadIdx.x;
  const int blockBase = blockIdx.x * SCHUNK;
  for (int i = t; i < nb; i += 256) hist[i] = 0;
  __syncthreads();
  const int lim = (nE - blockBase < SCHUNK) ? (nE - blockBase) : SCHUNK;
  for (int i = t; i < lim; i += 256)
    atomicAdd(&hist[dst[blockBase + i] >> 7], 1);
  __syncthreads();
  for (int i = t; i < nb; i += 256) {
    const int c = hist[i];
    base[i] = c ? (int)atomicAdd(&binCursor[i], (unsigned)c) : 0;
    hist[i] = 0;
  }
  __syncthreads();
  for (int i = t; i < lim; i += 256) {
    const int d = dst[blockBase + i];
    const int bin = d >> 7;
    const int loc = atomicAdd(&hist[bin], 1);
    const unsigned pos = (unsigned)base[bin] + (unsigned)loc;
    if (pos < BIN_CAP)
      ebuf[(size_t)bin * BIN_CAP + pos] =
          ((unsigned)src[blockBase + i] << 7) | (unsigned)(d & 127);
  }
}

// ---------------- per-bin max, D=128, bf16-packed pooled, ILP-8 ----------------
// LDS tile permuted: feat f -> word ((f&1)<<6)|(f>>1); ds ops conflict-free.
__global__ __launch_bounds__(512) void agg_bin128(
    const unsigned* __restrict__ ebuf, const unsigned* __restrict__ binCnt,
    const unsigned* __restrict__ pooled, float* __restrict__ agg, int n) {
  __shared__ unsigned tile[128 * 128];
  const int b = blockIdx.x;
  const int t = threadIdx.x;
  for (int i = t * 4; i < 16384; i += 2048)
    *(uint4*)&tile[i] = uint4{0u, 0u, 0u, 0u};
  __syncthreads();
  unsigned cnt = binCnt[b]; if (cnt > BIN_CAP) cnt = BIN_CAP;
  const int w = t >> 6, lane = t & 63;
  const unsigned* eb = ebuf + (size_t)b * BIN_CAP;
  unsigned e = (unsigned)w * 8;
  for (; e + 8 <= cnt; e += 64) {
    const uint4 ea = *(const uint4*)&eb[e];
    const uint4 eb4 = *(const uint4*)&eb[e + 4];
    const unsigned v0 = pooled[(size_t)(ea.x >> 7) * 64 + lane];
    const unsigned v1 = pooled[(size_t)(ea.y >> 7) * 64 + lane];
    const unsigned v2 = pooled[(size_t)(ea.z >> 7) * 64 + lane];
    const unsigned v3 = pooled[(size_t)(ea.w >> 7) * 64 + lane];
    const unsigned v4 = pooled[(size_t)(eb4.x >> 7) * 64 + lane];
    const unsigned v5 = pooled[(size_t)(eb4.y >> 7) * 64 + lane];
    const unsigned v6 = pooled[(size_t)(eb4.z >> 7) * 64 + lane];
    const unsigned v7 = pooled[(size_t)(eb4.w >> 7) * 64 + lane];
    unsigned* r0 = &tile[(ea.x & 127u) << 7];
    unsigned* r1 = &tile[(ea.y & 127u) << 7];
    unsigned* r2 = &tile[(ea.z & 127u) << 7];
    unsigned* r3 = &tile[(ea.w & 127u) << 7];
    unsigned* r4 = &tile[(eb4.x & 127u) << 7];
    unsigned* r5 = &tile[(eb4.y & 127u) << 7];
    unsigned* r6 = &tile[(eb4.z & 127u) << 7];
    unsigned* r7 = &tile[(eb4.w & 127u) << 7];
    atomicMax(&r0[lane], v0 << 16); atomicMax(&r0[64 + lane], v0 & 0xFFFF0000u);
    atomicMax(&r1[lane], v1 << 16); atomicMax(&r1[64 + lane], v1 & 0xFFFF0000u);
    atomicMax(&r2[lane], v2 << 16); atomicMax(&r2[64 + lane], v2 & 0xFFFF0000u);
    atomicMax(&r3[lane], v3 << 16); atomicMax(&r3[64 + lane], v3 & 0xFFFF0000u);
    atomicMax(&r4[lane], v4 << 16); atomicMax(&r4[64 + lane], v4 & 0xFFFF0000u);
    atomicMax(&r5[lane], v5 << 16); atomicMax(&r5[64 + lane], v5 & 0xFFFF0000u);
    atomicMax(&r6[lane], v6 << 16); atomicMax(&r6[64 + lane], v6 & 0xFFFF0000u);
    atomicMax(&r7[lane], v7 << 16); atomicMax(&r7[64 + lane], v7 & 0xFFFF0000u);
  }
  for (unsigned j = e; j < cnt && j < e + 8; ++j) {
    const unsigned word = eb[j];
    const unsigned v = pooled[(size_t)(word >> 7) * 64 + lane];
    unsigned* row = &tile[(word & 127u) << 7];
    atomicMax(&row[lane], v << 16);
    atomicMax(&row[64 + lane], v & 0xFFFF0000u);
  }
  __syncthreads();
  const int base = b << 7;
  for (int i = t * 4; i < 16384; i += 2048) {
    const int r = i >> 7, c = i & 127;
    if (base + r < n) {
      const unsigned* row = &tile[r << 7];
      uint4 o;
      o.x = row[(c >> 1) + 0];
      o.y = row[64 + (c >> 1) + 0];
      o.z = row[(c >> 1) + 1];
      o.w = row[64 + (c >> 1) + 1];
      *(uint4*)((unsigned*)agg + (size_t)(base + r) * 128 + c) = o;
    }
  }
}

// ---------------- per-bin max, D=64, fp32 pooled, ILP-8 ----------------
__global__ __launch_bounds__(512) void agg_bin64(
    const unsigned* __restrict__ ebuf, const unsigned* __restrict__ binCnt,
    const float* __restrict__ pooled, float* __restrict__ agg, int n) {
  __shared__ unsigned tile[128 * 64];
  const int b = blockIdx.x;
  const int t = threadIdx.x;
  for (int i = t * 4; i < 8192; i += 2048)
    *(uint4*)&tile[i] = uint4{0u, 0u, 0u, 0u};
  __syncthreads();
  unsigned cnt = binCnt[b]; if (cnt > BIN_CAP) cnt = BIN_CAP;
  const int w = t >> 6, lane = t & 63;
  const unsigned* eb = ebuf + (size_t)b * BIN_CAP;
  unsigned e = (unsigned)w * 8;
  for (; e + 8 <= cnt; e += 64) {
    const uint4 ea = *(const uint4*)&eb[e];
    const uint4 eb4 = *(const uint4*)&eb[e + 4];
    const unsigned v0 = __float_as_uint(pooled[(size_t)(ea.x >> 7) * 64 + lane]);
    const unsigned v1 = __float_as_uint(pooled[(size_t)(ea.y >> 7) * 64 + lane]);
    const unsigned v2 = __float_as_uint(pooled[(size_t)(ea.z >> 7) * 64 + lane]);
    const unsigned v3 = __float_as_uint(pooled[(size_t)(ea.w >> 7) * 64 + lane]);
    const unsigned v4 = __float_as_uint(pooled[(size_t)(eb4.x >> 7) * 64 + lane]);
    const unsigned v5 = __float_as_uint(pooled[(size_t)(eb4.y >> 7) * 64 + lane]);
    const unsigned v6 = __float_as_uint(pooled[(size_t)(eb4.z >> 7) * 64 + lane]);
    const unsigned v7 = __float_as_uint(pooled[(size_t)(eb4.w >> 7) * 64 + lane]);
    atomicMax(&tile[((ea.x & 127u) << 6) + lane], v0);
    atomicMax(&tile[((ea.y & 127u) << 6) + lane], v1);
    atomicMax(&tile[((ea.z & 127u) << 6) + lane], v2);
    atomicMax(&tile[((ea.w & 127u) << 6) + lane], v3);
    atomicMax(&tile[((eb4.x & 127u) << 6) + lane], v4);
    atomicMax(&tile[((eb4.y & 127u) << 6) + lane], v5);
    atomicMax(&tile[((eb4.z & 127u) << 6) + lane], v6);
    atomicMax(&tile[((eb4.w & 127u) << 6) + lane], v7);
  }
  for (unsigned j = e; j < cnt && j < e + 8; ++j) {
    const unsigned word = eb[j];
    const unsigned v = __float_as_uint(pooled[(size_t)(word >> 7) * 64 + lane]);
    atomicMax(&tile[((word & 127u) << 6) + lane], v);
  }
  __syncthreads();
  const int base = b << 7;
  for (int i = t * 4; i < 8192; i += 2048) {
    const int r = i >> 6;
    if (base + r < n)
      *(uint4*)((unsigned*)agg + (size_t)(base + r) * 64 + (i & 63)) =
          *(const uint4*)&tile[i];
  }
}

// ---------------- h = relu?(A @ Wa [+ G @ Wg] + bias), DOUT=64 ----------------
template <int DIN, bool DUAL, bool RELU>
__global__ __launch_bounds__(256) void gemm_h(
    const float* __restrict__ A, const float* __restrict__ Wa,
    const float* __restrict__ G, const float* __restrict__ Wg,
    const float* __restrict__ bias, float* __restrict__ out, int n) {
  __shared__ float S[DIN][68];
  const int t = threadIdx.x;
  const int row0 = blockIdx.x * 64;
  const int tr = t & 63;
  const int tk = t >> 6;
  const int cg = t & 15, rg = t >> 4;
  const int c0 = cg * 4;
  float acc[4][4] = {};
  int gr = row0 + tr; if (gr >= n) gr = n - 1;
  const int NPASS = DUAL ? 2 : 1;
  for (int pass = 0; pass < NPASS; ++pass) {
    const float* __restrict__ P = pass ? G : A;
    const float* __restrict__ W = pass ? Wg : Wa;
    constexpr int PER_T = DIN / 16;
#pragma unroll
    for (int i = 0; i < PER_T; ++i) {
      const int k4 = (tk * PER_T + i) * 4;
      const float4 v = *(const float4*)(P + (size_t)gr * DIN + k4);
      S[k4 + 0][tr] = v.x; S[k4 + 1][tr] = v.y;
      S[k4 + 2][tr] = v.z; S[k4 + 3][tr] = v.w;
    }
    __syncthreads();
#pragma unroll 4
    for (int k = 0; k < DIN; ++k) {
      const float4 w = *(const float4*)(W + k * 64 + c0);
      const float4 a = *(const float4*)(&S[k][rg * 4]);
      acc[0][0] = fmaf(a.x, w.x, acc[0][0]);
      acc[0][1] = fmaf(a.x, w.y, acc[0][1]);
      acc[0][2] = fmaf(a.x, w.z, acc[0][2]);
      acc[0][3] = fmaf(a.x, w.w, acc[0][3]);
      acc[1][0] = fmaf(a.y, w.x, acc[1][0]);
      acc[1][1] = fmaf(a.y, w.y, acc[1][1]);
      acc[1][2] = fmaf(a.y, w.z, acc[1][2]);
      acc[1][3] = fmaf(a.y, w.w, acc[1][3]);
      acc[2][0] = fmaf(a.z, w.x, acc[2][0]);
      acc[2][1] = fmaf(a.z, w.y, acc[2][1]);
      acc[2][2] = fmaf(a.z, w.z, acc[2][2]);
      acc[2][3] = fmaf(a.z, w.w, acc[2][3]);
      acc[3][0] = fmaf(a.w, w.x, acc[3][0]);
      acc[3][1] = fmaf(a.w, w.y, acc[3][1]);
      acc[3][2] = fmaf(a.w, w.z, acc[3][2]);
      acc[3][3] = fmaf(a.w, w.w, acc[3][3]);
    }
    if (pass + 1 < NPASS) __syncthreads();
  }
  const float4 bb = *(const float4*)(bias + c0);
#pragma unroll
  for (int r = 0; r < 4; ++r) {
    const int orow = row0 + rg * 4 + r;
    if (orow < n) {
      float4 o;
      o.x = acc[r][0] + bb.x;
      o.y = acc[r][1] + bb.y;
      o.z = acc[r][2] + bb.z;
      o.w = acc[r][3] + bb.w;
      if (RELU) {
        o.x = fmaxf(o.x, 0.f); o.y = fmaxf(o.y, 0.f);
        o.z = fmaxf(o.z, 0.f); o.w = fmaxf(o.w, 0.f);
      }
      *(float4*)(out + (size_t)orow * 64 + c0) = o;
    }
  }
}

// ---------------- out[N x 2] = h2 @ W_out + b_out ----------------
__global__ __launch_bounds__(256) void out_linear(
    const float* __restrict__ h, const float* __restrict__ W,
    const float* __restrict__ b, float* __restrict__ out, int n) {
  const int node = blockIdx.x * 256 + threadIdx.x;
  if (node >= n) return;
  float a0 = b[0], a1 = b[1];
#pragma unroll
  for (int k = 0; k < 64; k += 4) {
    const float4 hv = *(const float4*)(h + (size_t)node * 64 + k);
    a0 = fmaf(hv.x, W[(k + 0) * 2 + 0], a0);
    a1 = fmaf(hv.x, W[(k + 0) * 2 + 1], a1);
    a0 = fmaf(hv.y, W[(k + 1) * 2 + 0], a0);
    a1 = fmaf(hv.y, W[(k + 1) * 2 + 1], a1);
    a0 = fmaf(hv.z, W[(k + 2) * 2 + 0], a0);
    a1 = fmaf(hv.z, W[(k + 2) * 2 + 1], a1);
    a0 = fmaf(hv.w, W[(k + 3) * 2 + 0], a0);
    a1 = fmaf(hv.w, W[(k + 3) * 2 + 1], a1);
  }
  float2 o; o.x = a0; o.y = a1;
  *(float2*)(out + (size_t)node * 2) = o;
}

extern "C" void kernel_launch(void* const* d_in, const int* in_sizes, int n_in,
                              void* d_out, int out_size, void* d_ws, size_t ws_size,
                              hipStream_t stream) {
  const float* x       = (const float*)d_in[0];
  const int*   src     = (const int*)d_in[1];
  const int*   dst     = (const int*)d_in[2];
  const float* W_pool1 = (const float*)d_in[3];
  const float* b_pool1 = (const float*)d_in[4];
  const float* W_self1 = (const float*)d_in[5];
  const float* W_neigh1= (const float*)d_in[6];
  const float* b1      = (const float*)d_in[7];
  const float* W_pool2 = (const float*)d_in[8];
  const float* b_pool2 = (const float*)d_in[9];
  const float* W_self2 = (const float*)d_in[10];
  const float* W_neigh2= (const float*)d_in[11];
  const float* b2      = (const float*)d_in[12];
  const float* W_out   = (const float*)d_in[13];
  const float* b_out   = (const float*)d_in[14];

  const int n  = in_sizes[0] / 128;
  const int nE = in_sizes[1];
  const int NB = (n + 127) >> 7;

  // workspace layout:
  float* A = (float*)d_ws;                 // n*128 floats
  float* B = A + (size_t)n * 128;          // n*128 floats
  unsigned* ebuf = (unsigned*)(B + (size_t)n * 128);  // NB*BIN_CAP
  unsigned* binCursor = ebuf + (size_t)NB * BIN_CAP;  // NB

  unsigned* pooled1 = (unsigned*)A;        // n*64 words (bf16x2), dead after agg1
  float* h1      = A;                      // n*64 f (overwrites pooled1)
  float* pooled2 = A + (size_t)n * 64;     // n*64 f
  float* agg1    = B;                      // n*128 f, dead after gemm_h layer1
  float* agg2    = B;                      // n*64 f
  float* h2      = B + (size_t)n * 64;     // n*64 f
  float* outp    = (float*)d_out;

  // ---- bin build ----
  hipMemsetAsync(binCursor, 0, (size_t)NB * sizeof(unsigned), stream);
  bin_scatter2<<<(nE + SCHUNK - 1) / SCHUNK, 256, 0, stream>>>(
      src, dst, binCursor, ebuf, nE, NB);

  // ---- layer 1 ----
  gemm_pool1<<<(n + 31) / 32, 256, 0, stream>>>(x, W_pool1, b_pool1, pooled1, n);
  agg_bin128<<<NB, 512, 0, stream>>>(ebuf, binCursor, pooled1, agg1, n);
  gemm_h<128, true, true><<<(n + 63) / 64, 256, 0, stream>>>(
      x, W_self1, agg1, W_neigh1, b1, h1, n);

  // ---- layer 2 ----
  gemm_h<64, false, true><<<(n + 63) / 64, 256, 0, stream>>>(
      h1, W_pool2, nullptr, nullptr, b_pool2, pooled2, n);
  agg_bin64<<<NB, 512, 0, stream>>>(ebuf, binCursor, pooled2, agg2, n);
  gemm_h<64, true, true><<<(n + 63) / 64, 256, 0, stream>>>(
      h1, W_self2, agg2, W_neigh2, b2, h2, n);

  // ---- head ----
  out_linear<<<(n + 255) / 256, 256, 0, stream>>>(h2, W_out, b_out, outp, n);
}

// Round 5
// 358.748 us; speedup vs baseline: 2.8852x; 1.0277x over previous
//
#include <hip/hip_runtime.h>

// GraphSAGE (pool aggregator), 2 layers + linear head.
// N=100000, E=1600000, IN=128, H=64, C=2.
// GEMMs: W-in-LDS (64-k chunks), 4 nodes x 16 cols per thread, no global
// loads or barriers in the inner k loop.
// Edge aggregation: two-level 128-node dst binning, per-bin LDS-tile max
// with ds atomics, ILP-8. pooled1 packed bf16 to halve gather traffic.
// All maxes order-invariant -> deterministic output.

#define BIN_CAP 3072
#define MAX_BINS 1024
#define SCHUNK 8192

__device__ __forceinline__ unsigned bf16rne(float f) {
  const unsigned u = __float_as_uint(f);
  return (u + 0x7FFFu + ((u >> 16) & 1u)) >> 16;
}

// ---------------- GEMM: out = act(A@Wa [+ G@Wg] + bias) ----------------
// 256 threads; CG=DOUT/16 col-groups; each thread 4 nodes x 16 cols.
template <int DIN, int DOUT, bool DUAL, bool RELU, bool BF16OUT>
__global__ __launch_bounds__(256) void gemm_ws(
    const float* __restrict__ A, const float* __restrict__ Wa,
    const float* __restrict__ G, const float* __restrict__ Wg,
    const float* __restrict__ bias, void* __restrict__ out, int n) {
  constexpr int KC = 64;
  constexpr int CG = DOUT / 16;
  constexpr int NG = 256 / CG;
  constexpr int NPB = NG * 4;
  __shared__ float Ws[KC * DOUT];
  const int t = threadIdx.x;
  const int cg = t % CG, ng = t / CG;
  const int c0 = cg * 16;
  const int row0 = blockIdx.x * NPB;
  int node[4];
  bool ok[4];
#pragma unroll
  for (int r = 0; r < 4; ++r) {
    node[r] = row0 + ng + r * NG;
    ok[r] = node[r] < n;
    if (!ok[r]) node[r] = 0;
  }
  float acc[4][16];
#pragma unroll
  for (int r = 0; r < 4; ++r)
#pragma unroll
    for (int i = 0; i < 16; ++i) acc[r][i] = 0.f;

  const int NPASS = DUAL ? 2 : 1;
  for (int pass = 0; pass < NPASS; ++pass) {
    const float* __restrict__ P = pass ? G : A;
    const float* __restrict__ W = pass ? Wg : Wa;
    for (int kc = 0; kc < DIN; kc += KC) {
      __syncthreads();
#pragma unroll
      for (int i = 0; i < (KC * DOUT) / 1024; ++i) {
        const int ofs = t * 4 + i * 1024;
        *(float4*)&Ws[ofs] = *(const float4*)&W[(size_t)kc * DOUT + ofs];
      }
      __syncthreads();
#pragma unroll 2
      for (int k4 = 0; k4 < KC; k4 += 4) {
        float4 av[4];
#pragma unroll
        for (int r = 0; r < 4; ++r)
          av[r] = *(const float4*)(P + (size_t)node[r] * DIN + kc + k4);
#pragma unroll
        for (int j = 0; j < 4; ++j) {
          float a0 = ((const float*)&av[0])[j];
          float a1 = ((const float*)&av[1])[j];
          float a2 = ((const float*)&av[2])[j];
          float a3 = ((const float*)&av[3])[j];
#pragma unroll
          for (int i = 0; i < 4; ++i) {
            const float4 w = *(const float4*)&Ws[(k4 + j) * DOUT + c0 + i * 4];
            acc[0][i * 4 + 0] = fmaf(a0, w.x, acc[0][i * 4 + 0]);
            acc[0][i * 4 + 1] = fmaf(a0, w.y, acc[0][i * 4 + 1]);
            acc[0][i * 4 + 2] = fmaf(a0, w.z, acc[0][i * 4 + 2]);
            acc[0][i * 4 + 3] = fmaf(a0, w.w, acc[0][i * 4 + 3]);
            acc[1][i * 4 + 0] = fmaf(a1, w.x, acc[1][i * 4 + 0]);
            acc[1][i * 4 + 1] = fmaf(a1, w.y, acc[1][i * 4 + 1]);
            acc[1][i * 4 + 2] = fmaf(a1, w.z, acc[1][i * 4 + 2]);
            acc[1][i * 4 + 3] = fmaf(a1, w.w, acc[1][i * 4 + 3]);
            acc[2][i * 4 + 0] = fmaf(a2, w.x, acc[2][i * 4 + 0]);
            acc[2][i * 4 + 1] = fmaf(a2, w.y, acc[2][i * 4 + 1]);
            acc[2][i * 4 + 2] = fmaf(a2, w.z, acc[2][i * 4 + 2]);
            acc[2][i * 4 + 3] = fmaf(a2, w.w, acc[2][i * 4 + 3]);
            acc[3][i * 4 + 0] = fmaf(a3, w.x, acc[3][i * 4 + 0]);
            acc[3][i * 4 + 1] = fmaf(a3, w.y, acc[3][i * 4 + 1]);
            acc[3][i * 4 + 2] = fmaf(a3, w.z, acc[3][i * 4 + 2]);
            acc[3][i * 4 + 3] = fmaf(a3, w.w, acc[3][i * 4 + 3]);
          }
        }
      }
    }
  }
  float bb[16];
#pragma unroll
  for (int i = 0; i < 4; ++i)
    *(float4*)&bb[i * 4] = *(const float4*)(bias + c0 + i * 4);
#pragma unroll
  for (int r = 0; r < 4; ++r) {
    if (!ok[r]) continue;
    float v[16];
#pragma unroll
    for (int i = 0; i < 16; ++i) {
      v[i] = acc[r][i] + bb[i];
      if (RELU) v[i] = fmaxf(v[i], 0.f);
    }
    if (BF16OUT) {
      unsigned w[8];
#pragma unroll
      for (int i = 0; i < 8; ++i)
        w[i] = bf16rne(v[2 * i]) | (bf16rne(v[2 * i + 1]) << 16);
      unsigned* o = (unsigned*)out + (size_t)node[r] * (DOUT / 2) + (c0 >> 1);
      *(uint4*)&o[0] = *(uint4*)&w[0];
      *(uint4*)&o[4] = *(uint4*)&w[4];
    } else {
      float* o = (float*)out + (size_t)node[r] * DOUT + c0;
#pragma unroll
      for (int i = 0; i < 4; ++i) *(float4*)&o[i * 4] = *(float4*)&v[i * 4];
    }
  }
}

// ---------------- two-level bin scatter ----------------
__global__ __launch_bounds__(256) void bin_scatter2(
    const int* __restrict__ src, const int* __restrict__ dst,
    unsigned* __restrict__ binCursor, unsigned* __restrict__ ebuf,
    int nE, int nb) {
  __shared__ int hist[MAX_BINS];
  __shared__ int base[MAX_BINS];
  const int t = threadIdx.x;
  const int blockBase = blockIdx.x * SCHUNK;
  for (int i = t; i < nb; i += 256) hist[i] = 0;
  __syncthreads();
  const int lim = (nE - blockBase < SCHUNK) ? (nE - blockBase) : SCHUNK;
  for (int i = t; i < lim; i += 256)
    atomicAdd(&hist[dst[blockBase + i] >> 7], 1);
  __syncthreads();
  for (int i = t; i < nb; i += 256) {
    const int c = hist[i];
    base[i] = c ? (int)atomicAdd(&binCursor[i], (unsigned)c) : 0;
    hist[i] = 0;
  }
  __syncthreads();
  for (int i = t; i < lim; i += 256) {
    const int d = dst[blockBase + i];
    const int bin = d >> 7;
    const int loc = atomicAdd(&hist[bin], 1);
    const unsigned pos = (unsigned)base[bin] + (unsigned)loc;
    if (pos < BIN_CAP)
      ebuf[(size_t)bin * BIN_CAP + pos] =
          ((unsigned)src[blockBase + i] << 7) | (unsigned)(d & 127);
  }
}

// ---------------- per-bin max, D=128, bf16-packed pooled, ILP-8 ----------------
__global__ __launch_bounds__(512) void agg_bin128(
    const unsigned* __restrict__ ebuf, const unsigned* __restrict__ binCnt,
    const unsigned* __restrict__ pooled, float* __restrict__ agg, int n) {
  __shared__ unsigned tile[128 * 128];
  const int b = blockIdx.x;
  const int t = threadIdx.x;
  for (int i = t * 4; i < 16384; i += 2048)
    *(uint4*)&tile[i] = uint4{0u, 0u, 0u, 0u};
  __syncthreads();
  unsigned cnt = binCnt[b]; if (cnt > BIN_CAP) cnt = BIN_CAP;
  const int w = t >> 6, lane = t & 63;
  const unsigned* eb = ebuf + (size_t)b * BIN_CAP;
  unsigned e = (unsigned)w * 8;
  for (; e + 8 <= cnt; e += 64) {
    const uint4 ea = *(const uint4*)&eb[e];
    const uint4 eb4 = *(const uint4*)&eb[e + 4];
    const unsigned v0 = pooled[(size_t)(ea.x >> 7) * 64 + lane];
    const unsigned v1 = pooled[(size_t)(ea.y >> 7) * 64 + lane];
    const unsigned v2 = pooled[(size_t)(ea.z >> 7) * 64 + lane];
    const unsigned v3 = pooled[(size_t)(ea.w >> 7) * 64 + lane];
    const unsigned v4 = pooled[(size_t)(eb4.x >> 7) * 64 + lane];
    const unsigned v5 = pooled[(size_t)(eb4.y >> 7) * 64 + lane];
    const unsigned v6 = pooled[(size_t)(eb4.z >> 7) * 64 + lane];
    const unsigned v7 = pooled[(size_t)(eb4.w >> 7) * 64 + lane];
    unsigned* r0 = &tile[(ea.x & 127u) << 7];
    unsigned* r1 = &tile[(ea.y & 127u) << 7];
    unsigned* r2 = &tile[(ea.z & 127u) << 7];
    unsigned* r3 = &tile[(ea.w & 127u) << 7];
    unsigned* r4 = &tile[(eb4.x & 127u) << 7];
    unsigned* r5 = &tile[(eb4.y & 127u) << 7];
    unsigned* r6 = &tile[(eb4.z & 127u) << 7];
    unsigned* r7 = &tile[(eb4.w & 127u) << 7];
    atomicMax(&r0[lane], v0 << 16); atomicMax(&r0[64 + lane], v0 & 0xFFFF0000u);
    atomicMax(&r1[lane], v1 << 16); atomicMax(&r1[64 + lane], v1 & 0xFFFF0000u);
    atomicMax(&r2[lane], v2 << 16); atomicMax(&r2[64 + lane], v2 & 0xFFFF0000u);
    atomicMax(&r3[lane], v3 << 16); atomicMax(&r3[64 + lane], v3 & 0xFFFF0000u);
    atomicMax(&r4[lane], v4 << 16); atomicMax(&r4[64 + lane], v4 & 0xFFFF0000u);
    atomicMax(&r5[lane], v5 << 16); atomicMax(&r5[64 + lane], v5 & 0xFFFF0000u);
    atomicMax(&r6[lane], v6 << 16); atomicMax(&r6[64 + lane], v6 & 0xFFFF0000u);
    atomicMax(&r7[lane], v7 << 16); atomicMax(&r7[64 + lane], v7 & 0xFFFF0000u);
  }
  for (unsigned j = e; j < cnt && j < e + 8; ++j) {
    const unsigned word = eb[j];
    const unsigned v = pooled[(size_t)(word >> 7) * 64 + lane];
    unsigned* row = &tile[(word & 127u) << 7];
    atomicMax(&row[lane], v << 16);
    atomicMax(&row[64 + lane], v & 0xFFFF0000u);
  }
  __syncthreads();
  const int base = b << 7;
  for (int i = t * 4; i < 16384; i += 2048) {
    const int r = i >> 7, c = i & 127;
    if (base + r < n) {
      const unsigned* row = &tile[r << 7];
      uint4 o;
      o.x = row[(c >> 1) + 0];
      o.y = row[64 + (c >> 1) + 0];
      o.z = row[(c >> 1) + 1];
      o.w = row[64 + (c >> 1) + 1];
      *(uint4*)((unsigned*)agg + (size_t)(base + r) * 128 + c) = o;
    }
  }
}

// ---------------- per-bin max, D=64, fp32 pooled, ILP-8 ----------------
__global__ __launch_bounds__(512) void agg_bin64(
    const unsigned* __restrict__ ebuf, const unsigned* __restrict__ binCnt,
    const float* __restrict__ pooled, float* __restrict__ agg, int n) {
  __shared__ unsigned tile[128 * 64];
  const int b = blockIdx.x;
  const int t = threadIdx.x;
  for (int i = t * 4; i < 8192; i += 2048)
    *(uint4*)&tile[i] = uint4{0u, 0u, 0u, 0u};
  __syncthreads();
  unsigned cnt = binCnt[b]; if (cnt > BIN_CAP) cnt = BIN_CAP;
  const int w = t >> 6, lane = t & 63;
  const unsigned* eb = ebuf + (size_t)b * BIN_CAP;
  unsigned e = (unsigned)w * 8;
  for (; e + 8 <= cnt; e += 64) {
    const uint4 ea = *(const uint4*)&eb[e];
    const uint4 eb4 = *(const uint4*)&eb[e + 4];
    const unsigned v0 = __float_as_uint(pooled[(size_t)(ea.x >> 7) * 64 + lane]);
    const unsigned v1 = __float_as_uint(pooled[(size_t)(ea.y >> 7) * 64 + lane]);
    const unsigned v2 = __float_as_uint(pooled[(size_t)(ea.z >> 7) * 64 + lane]);
    const unsigned v3 = __float_as_uint(pooled[(size_t)(ea.w >> 7) * 64 + lane]);
    const unsigned v4 = __float_as_uint(pooled[(size_t)(eb4.x >> 7) * 64 + lane]);
    const unsigned v5 = __float_as_uint(pooled[(size_t)(eb4.y >> 7) * 64 + lane]);
    const unsigned v6 = __float_as_uint(pooled[(size_t)(eb4.z >> 7) * 64 + lane]);
    const unsigned v7 = __float_as_uint(pooled[(size_t)(eb4.w >> 7) * 64 + lane]);
    atomicMax(&tile[((ea.x & 127u) << 6) + lane], v0);
    atomicMax(&tile[((ea.y & 127u) << 6) + lane], v1);
    atomicMax(&tile[((ea.z & 127u) << 6) + lane], v2);
    atomicMax(&tile[((ea.w & 127u) << 6) + lane], v3);
    atomicMax(&tile[((eb4.x & 127u) << 6) + lane], v4);
    atomicMax(&tile[((eb4.y & 127u) << 6) + lane], v5);
    atomicMax(&tile[((eb4.z & 127u) << 6) + lane], v6);
    atomicMax(&tile[((eb4.w & 127u) << 6) + lane], v7);
  }
  for (unsigned j = e; j < cnt && j < e + 8; ++j) {
    const unsigned word = eb[j];
    const unsigned v = __float_as_uint(pooled[(size_t)(word >> 7) * 64 + lane]);
    atomicMax(&tile[((word & 127u) << 6) + lane], v);
  }
  __syncthreads();
  const int base = b << 7;
  for (int i = t * 4; i < 8192; i += 2048) {
    const int r = i >> 6;
    if (base + r < n)
      *(uint4*)((unsigned*)agg + (size_t)(base + r) * 64 + (i & 63)) =
          *(const uint4*)&tile[i];
  }
}

// ---------------- out[N x 2] = h2 @ W_out + b_out ----------------
__global__ __launch_bounds__(256) void out_linear(
    const float* __restrict__ h, const float* __restrict__ W,
    const float* __restrict__ b, float* __restrict__ out, int n) {
  const int node = blockIdx.x * 256 + threadIdx.x;
  if (node >= n) return;
  float a0 = b[0], a1 = b[1];
#pragma unroll
  for (int k = 0; k < 64; k += 4) {
    const float4 hv = *(const float4*)(h + (size_t)node * 64 + k);
    a0 = fmaf(hv.x, W[(k + 0) * 2 + 0], a0);
    a1 = fmaf(hv.x, W[(k + 0) * 2 + 1], a1);
    a0 = fmaf(hv.y, W[(k + 1) * 2 + 0], a0);
    a1 = fmaf(hv.y, W[(k + 1) * 2 + 1], a1);
    a0 = fmaf(hv.z, W[(k + 2) * 2 + 0], a0);
    a1 = fmaf(hv.z, W[(k + 2) * 2 + 1], a1);
    a0 = fmaf(hv.w, W[(k + 3) * 2 + 0], a0);
    a1 = fmaf(hv.w, W[(k + 3) * 2 + 1], a1);
  }
  float2 o; o.x = a0; o.y = a1;
  *(float2*)(out + (size_t)node * 2) = o;
}

extern "C" void kernel_launch(void* const* d_in, const int* in_sizes, int n_in,
                              void* d_out, int out_size, void* d_ws, size_t ws_size,
                              hipStream_t stream) {
  const float* x       = (const float*)d_in[0];
  const int*   src     = (const int*)d_in[1];
  const int*   dst     = (const int*)d_in[2];
  const float* W_pool1 = (const float*)d_in[3];
  const float* b_pool1 = (const float*)d_in[4];
  const float* W_self1 = (const float*)d_in[5];
  const float* W_neigh1= (const float*)d_in[6];
  const float* b1      = (const float*)d_in[7];
  const float* W_pool2 = (const float*)d_in[8];
  const float* b_pool2 = (const float*)d_in[9];
  const float* W_self2 = (const float*)d_in[10];
  const float* W_neigh2= (const float*)d_in[11];
  const float* b2      = (const float*)d_in[12];
  const float* W_out   = (const float*)d_in[13];
  const float* b_out   = (const float*)d_in[14];

  const int n  = in_sizes[0] / 128;
  const int nE = in_sizes[1];
  const int NB = (n + 127) >> 7;

  // workspace layout:
  float* A = (float*)d_ws;                 // n*128 floats
  float* B = A + (size_t)n * 128;          // n*128 floats
  unsigned* ebuf = (unsigned*)(B + (size_t)n * 128);  // NB*BIN_CAP
  unsigned* binCursor = ebuf + (size_t)NB * BIN_CAP;  // NB

  unsigned* pooled1 = (unsigned*)A;        // n*64 words (bf16x2), dead after agg1
  float* h1      = A;                      // n*64 f (overwrites pooled1)
  float* pooled2 = A + (size_t)n * 64;     // n*64 f
  float* agg1    = B;                      // n*128 f, dead after layer-1 gemm
  float* agg2    = B;                      // n*64 f
  float* h2      = B + (size_t)n * 64;     // n*64 f
  float* outp    = (float*)d_out;

  // ---- bin build ----
  hipMemsetAsync(binCursor, 0, (size_t)NB * sizeof(unsigned), stream);
  bin_scatter2<<<(nE + SCHUNK - 1) / SCHUNK, 256, 0, stream>>>(
      src, dst, binCursor, ebuf, nE, NB);

  // ---- layer 1 ----
  gemm_ws<128, 128, false, true, true><<<(n + 127) / 128, 256, 0, stream>>>(
      x, W_pool1, nullptr, nullptr, b_pool1, pooled1, n);
  agg_bin128<<<NB, 512, 0, stream>>>(ebuf, binCursor, pooled1, agg1, n);
  gemm_ws<128, 64, true, true, false><<<(n + 255) / 256, 256, 0, stream>>>(
      x, W_self1, agg1, W_neigh1, b1, h1, n);

  // ---- layer 2 ----
  gemm_ws<64, 64, false, true, false><<<(n + 255) / 256, 256, 0, stream>>>(
      h1, W_pool2, nullptr, nullptr, b_pool2, pooled2, n);
  agg_bin64<<<NB, 512, 0, stream>>>(ebuf, binCursor, pooled2, agg2, n);
  gemm_ws<64, 64, true, true, false><<<(n + 255) / 256, 256, 0, stream>>>(
      h1, W_self2, agg2, W_neigh2, b2, h2, n);

  // ---- head ----
  out_linear<<<(n + 255) / 256, 256, 0, stream>>>(h2, W_out, b_out, outp, n);
}

// Round 6
// 311.086 us; speedup vs baseline: 3.3273x; 1.1532x over previous
//
#include <hip/hip_runtime.h>

// GraphSAGE (pool aggregator), 2 layers + linear head.
// N=100000, E=1600000, IN=128, H=64, C=2.
// GEMMs: W-in-LDS (64-k chunks), 4 nodes x 16 cols per thread, A-loads
// software-pipelined (prefetch next k4 before FMA block).
// Edge aggregation: two-level 128-node dst binning; per-bin LDS-tile max
// (32 KB tiles, 2 edges per wave, bf16-packed pooled for both layers).
// All maxes order-invariant -> deterministic output.

#define BIN_CAP 3072
#define MAX_BINS 1024
#define SCHUNK 8192

__device__ __forceinline__ unsigned bf16rne(float f) {
  const unsigned u = __float_as_uint(f);
  return (u + 0x7FFFu + ((u >> 16) & 1u)) >> 16;
}

// ---------------- GEMM: out = act(A@Wa [+ G@Wg] + bias) ----------------
// 256 threads; CG=DOUT/16 col-groups; each thread 4 nodes x 16 cols.
template <int DIN, int DOUT, bool DUAL, bool RELU, bool BF16OUT>
__global__ __launch_bounds__(256) void gemm_ws(
    const float* __restrict__ A, const float* __restrict__ Wa,
    const float* __restrict__ G, const float* __restrict__ Wg,
    const float* __restrict__ bias, void* __restrict__ out, int n) {
  constexpr int KC = 64;
  constexpr int CG = DOUT / 16;
  constexpr int NG = 256 / CG;
  constexpr int NPB = NG * 4;
  __shared__ float Ws[KC * DOUT];
  const int t = threadIdx.x;
  const int cg = t % CG, ng = t / CG;
  const int c0 = cg * 16;
  const int row0 = blockIdx.x * NPB;
  int node[4];
  bool ok[4];
#pragma unroll
  for (int r = 0; r < 4; ++r) {
    node[r] = row0 + ng + r * NG;
    ok[r] = node[r] < n;
    if (!ok[r]) node[r] = 0;
  }
  float acc[4][16];
#pragma unroll
  for (int r = 0; r < 4; ++r)
#pragma unroll
    for (int i = 0; i < 16; ++i) acc[r][i] = 0.f;

  auto fmablk = [&](int k4, const float4* av_) {
#pragma unroll
    for (int j = 0; j < 4; ++j) {
      const float a0 = ((const float*)&av_[0])[j];
      const float a1 = ((const float*)&av_[1])[j];
      const float a2 = ((const float*)&av_[2])[j];
      const float a3 = ((const float*)&av_[3])[j];
#pragma unroll
      for (int i = 0; i < 4; ++i) {
        const float4 w = *(const float4*)&Ws[(k4 + j) * DOUT + c0 + i * 4];
        acc[0][i * 4 + 0] = fmaf(a0, w.x, acc[0][i * 4 + 0]);
        acc[0][i * 4 + 1] = fmaf(a0, w.y, acc[0][i * 4 + 1]);
        acc[0][i * 4 + 2] = fmaf(a0, w.z, acc[0][i * 4 + 2]);
        acc[0][i * 4 + 3] = fmaf(a0, w.w, acc[0][i * 4 + 3]);
        acc[1][i * 4 + 0] = fmaf(a1, w.x, acc[1][i * 4 + 0]);
        acc[1][i * 4 + 1] = fmaf(a1, w.y, acc[1][i * 4 + 1]);
        acc[1][i * 4 + 2] = fmaf(a1, w.z, acc[1][i * 4 + 2]);
        acc[1][i * 4 + 3] = fmaf(a1, w.w, acc[1][i * 4 + 3]);
        acc[2][i * 4 + 0] = fmaf(a2, w.x, acc[2][i * 4 + 0]);
        acc[2][i * 4 + 1] = fmaf(a2, w.y, acc[2][i * 4 + 1]);
        acc[2][i * 4 + 2] = fmaf(a2, w.z, acc[2][i * 4 + 2]);
        acc[2][i * 4 + 3] = fmaf(a2, w.w, acc[2][i * 4 + 3]);
        acc[3][i * 4 + 0] = fmaf(a3, w.x, acc[3][i * 4 + 0]);
        acc[3][i * 4 + 1] = fmaf(a3, w.y, acc[3][i * 4 + 1]);
        acc[3][i * 4 + 2] = fmaf(a3, w.z, acc[3][i * 4 + 2]);
        acc[3][i * 4 + 3] = fmaf(a3, w.w, acc[3][i * 4 + 3]);
      }
    }
  };

  const int NPASS = DUAL ? 2 : 1;
  for (int pass = 0; pass < NPASS; ++pass) {
    const float* __restrict__ P = pass ? G : A;
    const float* __restrict__ W = pass ? Wg : Wa;
    for (int kc = 0; kc < DIN; kc += KC) {
      __syncthreads();
#pragma unroll
      for (int i = 0; i < (KC * DOUT) / 1024; ++i) {
        const int ofs = t * 4 + i * 1024;
        *(float4*)&Ws[ofs] = *(const float4*)&W[(size_t)kc * DOUT + ofs];
      }
      __syncthreads();
      float4 av[4];
#pragma unroll
      for (int r = 0; r < 4; ++r)
        av[r] = *(const float4*)(P + (size_t)node[r] * DIN + kc);
#pragma unroll 2
      for (int k4 = 0; k4 < KC - 4; k4 += 4) {
        float4 avn[4];
#pragma unroll
        for (int r = 0; r < 4; ++r)
          avn[r] = *(const float4*)(P + (size_t)node[r] * DIN + kc + k4 + 4);
        fmablk(k4, av);
#pragma unroll
        for (int r = 0; r < 4; ++r) av[r] = avn[r];
      }
      fmablk(KC - 4, av);
    }
  }
  float bb[16];
#pragma unroll
  for (int i = 0; i < 4; ++i)
    *(float4*)&bb[i * 4] = *(const float4*)(bias + c0 + i * 4);
#pragma unroll
  for (int r = 0; r < 4; ++r) {
    if (!ok[r]) continue;
    float v[16];
#pragma unroll
    for (int i = 0; i < 16; ++i) {
      v[i] = acc[r][i] + bb[i];
      if (RELU) v[i] = fmaxf(v[i], 0.f);
    }
    if (BF16OUT) {
      unsigned w[8];
#pragma unroll
      for (int i = 0; i < 8; ++i)
        w[i] = bf16rne(v[2 * i]) | (bf16rne(v[2 * i + 1]) << 16);
      unsigned* o = (unsigned*)out + (size_t)node[r] * (DOUT / 2) + (c0 >> 1);
      *(uint4*)&o[0] = *(uint4*)&w[0];
      *(uint4*)&o[4] = *(uint4*)&w[4];
    } else {
      float* o = (float*)out + (size_t)node[r] * DOUT + c0;
#pragma unroll
      for (int i = 0; i < 4; ++i) *(float4*)&o[i * 4] = *(float4*)&v[i * 4];
    }
  }
}

// ---------------- two-level bin scatter ----------------
__global__ __launch_bounds__(256) void bin_scatter2(
    const int* __restrict__ src, const int* __restrict__ dst,
    unsigned* __restrict__ binCursor, unsigned* __restrict__ ebuf,
    int nE, int nb) {
  __shared__ int hist[MAX_BINS];
  __shared__ int base[MAX_BINS];
  const int t = threadIdx.x;
  const int blockBase = blockIdx.x * SCHUNK;
  for (int i = t; i < nb; i += 256) hist[i] = 0;
  __syncthreads();
  const int lim = (nE - blockBase < SCHUNK) ? (nE - blockBase) : SCHUNK;
  for (int i = t; i < lim; i += 256)
    atomicAdd(&hist[dst[blockBase + i] >> 7], 1);
  __syncthreads();
  for (int i = t; i < nb; i += 256) {
    const int c = hist[i];
    base[i] = c ? (int)atomicAdd(&binCursor[i], (unsigned)c) : 0;
    hist[i] = 0;
  }
  __syncthreads();
  for (int i = t; i < lim; i += 256) {
    const int d = dst[blockBase + i];
    const int bin = d >> 7;
    const int loc = atomicAdd(&hist[bin], 1);
    const unsigned pos = (unsigned)base[bin] + (unsigned)loc;
    if (pos < BIN_CAP)
      ebuf[(size_t)bin * BIN_CAP + pos] =
          ((unsigned)src[blockBase + i] << 7) | (unsigned)(d & 127);
  }
}

// ---------------- per-bin max over bf16-packed pooled ----------------
// POOLW = words per pooled row; STRIDE = agg row stride (floats);
// NH = feature-half blocks per bin (blockIdx.y = half).
// Tile: 128 nodes x 64 f32 words (32 KB); node row: word c = even feat 2c,
// word 32+c = odd feat 2c+1 (c=0..31). Wave processes 2 edges at once
// (lanes 0-31 / 32-63); row stride 256B -> 2 lanes/bank = conflict-free.
template <int POOLW, int STRIDE, int NH>
__global__ __launch_bounds__(512) void agg_bin(
    const unsigned* __restrict__ ebuf, const unsigned* __restrict__ binCnt,
    const unsigned* __restrict__ pooled, float* __restrict__ agg, int n) {
  __shared__ unsigned tile[128 * 64];
  const int b = blockIdx.x;
  const int half = (NH > 1) ? (int)blockIdx.y : 0;
  const int word_ofs = half * 32;
  const int feat_base = half * 64;
  const int t = threadIdx.x;
  for (int i = t * 4; i < 8192; i += 2048)
    *(uint4*)&tile[i] = uint4{0u, 0u, 0u, 0u};
  __syncthreads();
  unsigned cnt = binCnt[b]; if (cnt > BIN_CAP) cnt = BIN_CAP;
  const int w = t >> 6, lane = t & 63;
  const int l31 = lane & 31;
  const bool hi = lane >= 32;
  const unsigned* eb = ebuf + (size_t)b * BIN_CAP;
  unsigned e = (unsigned)w * 8;
  for (; e + 8 <= cnt; e += 64) {
    const uint4 ea = *(const uint4*)&eb[e];
    const uint4 eb4 = *(const uint4*)&eb[e + 4];
    const unsigned w0 = hi ? ea.y : ea.x;
    const unsigned w1 = hi ? ea.w : ea.z;
    const unsigned w2 = hi ? eb4.y : eb4.x;
    const unsigned w3 = hi ? eb4.w : eb4.z;
    const unsigned v0 = pooled[(size_t)(w0 >> 7) * POOLW + word_ofs + l31];
    const unsigned v1 = pooled[(size_t)(w1 >> 7) * POOLW + word_ofs + l31];
    const unsigned v2 = pooled[(size_t)(w2 >> 7) * POOLW + word_ofs + l31];
    const unsigned v3 = pooled[(size_t)(w3 >> 7) * POOLW + word_ofs + l31];
    unsigned* r0 = &tile[(w0 & 127u) << 6];
    unsigned* r1 = &tile[(w1 & 127u) << 6];
    unsigned* r2 = &tile[(w2 & 127u) << 6];
    unsigned* r3 = &tile[(w3 & 127u) << 6];
    atomicMax(&r0[l31], v0 << 16); atomicMax(&r0[32 + l31], v0 & 0xFFFF0000u);
    atomicMax(&r1[l31], v1 << 16); atomicMax(&r1[32 + l31], v1 & 0xFFFF0000u);
    atomicMax(&r2[l31], v2 << 16); atomicMax(&r2[32 + l31], v2 & 0xFFFF0000u);
    atomicMax(&r3[l31], v3 << 16); atomicMax(&r3[32 + l31], v3 & 0xFFFF0000u);
  }
  for (unsigned j = e; j < cnt && j < e + 8; ++j) {
    // tail: all 64 lanes process the same edge (duplicate atomics harmless)
    const unsigned wd = eb[j];
    const unsigned v = pooled[(size_t)(wd >> 7) * POOLW + word_ofs + l31];
    unsigned* row = &tile[(wd & 127u) << 6];
    atomicMax(&row[l31], v << 16);
    atomicMax(&row[32 + l31], v & 0xFFFF0000u);
  }
  __syncthreads();
  const int base = b << 7;
  for (int g = t; g < 2048; g += 512) {
    const int r = g >> 4, q = g & 15;
    if (base + r < n) {
      const unsigned* row = &tile[r << 6];
      const int c = q * 2;
      uint4 o;
      o.x = row[c];
      o.y = row[32 + c];
      o.z = row[c + 1];
      o.w = row[32 + c + 1];
      *(uint4*)((unsigned*)agg + (size_t)(base + r) * STRIDE + feat_base + q * 4) = o;
    }
  }
}

// ---------------- out[N x 2] = h2 @ W_out + b_out ----------------
__global__ __launch_bounds__(256) void out_linear(
    const float* __restrict__ h, const float* __restrict__ W,
    const float* __restrict__ b, float* __restrict__ out, int n) {
  const int node = blockIdx.x * 256 + threadIdx.x;
  if (node >= n) return;
  float a0 = b[0], a1 = b[1];
#pragma unroll
  for (int k = 0; k < 64; k += 4) {
    const float4 hv = *(const float4*)(h + (size_t)node * 64 + k);
    a0 = fmaf(hv.x, W[(k + 0) * 2 + 0], a0);
    a1 = fmaf(hv.x, W[(k + 0) * 2 + 1], a1);
    a0 = fmaf(hv.y, W[(k + 1) * 2 + 0], a0);
    a1 = fmaf(hv.y, W[(k + 1) * 2 + 1], a1);
    a0 = fmaf(hv.z, W[(k + 2) * 2 + 0], a0);
    a1 = fmaf(hv.z, W[(k + 2) * 2 + 1], a1);
    a0 = fmaf(hv.w, W[(k + 3) * 2 + 0], a0);
    a1 = fmaf(hv.w, W[(k + 3) * 2 + 1], a1);
  }
  float2 o; o.x = a0; o.y = a1;
  *(float2*)(out + (size_t)node * 2) = o;
}

extern "C" void kernel_launch(void* const* d_in, const int* in_sizes, int n_in,
                              void* d_out, int out_size, void* d_ws, size_t ws_size,
                              hipStream_t stream) {
  const float* x       = (const float*)d_in[0];
  const int*   src     = (const int*)d_in[1];
  const int*   dst     = (const int*)d_in[2];
  const float* W_pool1 = (const float*)d_in[3];
  const float* b_pool1 = (const float*)d_in[4];
  const float* W_self1 = (const float*)d_in[5];
  const float* W_neigh1= (const float*)d_in[6];
  const float* b1      = (const float*)d_in[7];
  const float* W_pool2 = (const float*)d_in[8];
  const float* b_pool2 = (const float*)d_in[9];
  const float* W_self2 = (const float*)d_in[10];
  const float* W_neigh2= (const float*)d_in[11];
  const float* b2      = (const float*)d_in[12];
  const float* W_out   = (const float*)d_in[13];
  const float* b_out   = (const float*)d_in[14];

  const int n  = in_sizes[0] / 128;
  const int nE = in_sizes[1];
  const int NB = (n + 127) >> 7;

  // workspace layout:
  float* A = (float*)d_ws;                 // n*128 floats
  float* B = A + (size_t)n * 128;          // n*128 floats
  unsigned* ebuf = (unsigned*)(B + (size_t)n * 128);  // NB*BIN_CAP
  unsigned* binCursor = ebuf + (size_t)NB * BIN_CAP;  // NB

  unsigned* pooled1 = (unsigned*)A;        // n*64 words (bf16x2), dead after agg1
  float* h1      = A;                      // n*64 f (overwrites pooled1)
  unsigned* pooled2 = (unsigned*)(A + (size_t)n * 64);  // n*32 words (bf16x2)
  float* agg1    = B;                      // n*128 f, dead after layer-1 gemm
  float* agg2    = B;                      // n*64 f
  float* h2      = B + (size_t)n * 64;     // n*64 f
  float* outp    = (float*)d_out;

  // ---- bin build ----
  hipMemsetAsync(binCursor, 0, (size_t)NB * sizeof(unsigned), stream);
  bin_scatter2<<<(nE + SCHUNK - 1) / SCHUNK, 256, 0, stream>>>(
      src, dst, binCursor, ebuf, nE, NB);

  // ---- layer 1 ----
  gemm_ws<128, 128, false, true, true><<<(n + 127) / 128, 256, 0, stream>>>(
      x, W_pool1, nullptr, nullptr, b_pool1, pooled1, n);
  agg_bin<64, 128, 2><<<dim3(NB, 2), 512, 0, stream>>>(
      ebuf, binCursor, pooled1, agg1, n);
  gemm_ws<128, 64, true, true, false><<<(n + 255) / 256, 256, 0, stream>>>(
      x, W_self1, agg1, W_neigh1, b1, h1, n);

  // ---- layer 2 ----
  gemm_ws<64, 64, false, true, true><<<(n + 255) / 256, 256, 0, stream>>>(
      h1, W_pool2, nullptr, nullptr, b_pool2, pooled2, n);
  agg_bin<32, 64, 1><<<dim3(NB, 1), 512, 0, stream>>>(
      ebuf, binCursor, pooled2, agg2, n);
  gemm_ws<64, 64, true, true, false><<<(n + 255) / 256, 256, 0, stream>>>(
      h1, W_self2, agg2, W_neigh2, b2, h2, n);

  // ---- head ----
  out_linear<<<(n + 255) / 256, 256, 0, stream>>>(h2, W_out, b_out, outp, n);
}